// Round 15
// baseline (50.785 us; speedup 1.0000x reference)
//
#include <hip/hip_runtime.h>

#define DTF (1.0f/120.0f)

constexpr int Bn = 2048, Tn = 2048, NS = Tn - 1, ZF = Tn * 3;
constexpr int BT = 64;                 // one wave; 2 trajectories x 32 time-chunks
constexpr int NBLK = Bn / 2;           // 1024 blocks
constexpr int GRAN = ZF / 4;           // 1536 16B-granules per trajectory
constexpr int RROWS = 128;             // gain rows (span per lane)

// ws: [0,4096) gain table (128 x 8 floats); [4096,...) 1024 doubles partials
constexpr int WS_PART = 4096;

__device__ __forceinline__ int swz(int q) { return q ^ ((q >> 5) & 31); }

// ---- gains: serial 2x2 Riccati from P0, 128 rows {kx0,kx1,kt0,kt1,isx,ist,det,0} ----
__global__ void gains_kernel(const float* __restrict__ params, float* __restrict__ gt)
{
    if (threadIdx.x != 0) return;
    const float dt = DTF;
    const float damping = params[1];
    const float a = 1.f - dt * damping;
    const float dt2 = dt * dt, a2 = a * a;
    const float qp = 2e-10f, qv = 3e-7f, qth = 1e-2f, qdth = 1e-1f;
    const float Rp = 2.5e-7f, Rt = 9.1e-3f;
    float x00 = 0.01f, x01 = 0.f, x11 = 0.01f;
    float t00 = 0.01f, t01 = 0.f, t11 = 0.01f;
    for (int t = 0; t < RROWS; ++t) {
        float Pp00 = fmaf(dt2, x11, fmaf(2.f * dt, x01, x00)) + qp;
        float Pp01 = a * fmaf(dt, x11, x01);
        float Pp11 = fmaf(a2, x11, qv);
        float Sx = Pp00 + Rp, isx = __builtin_amdgcn_rcpf(Sx);
        float kx0 = Pp00 * isx, kx1 = Pp01 * isx;
        x00 = Pp00 - kx0 * Pp00; x01 = Pp01 - kx0 * Pp01; x11 = Pp11 - kx1 * Pp01;
        float Tp00 = fmaf(dt2, t11, fmaf(2.f * dt, t01, t00)) + qth;
        float Tp01 = fmaf(dt, t11, t01);
        float Tp11 = t11 + qdth;
        float St = Tp00 + Rt, ist = __builtin_amdgcn_rcpf(St);
        float kt0 = Tp00 * ist, kt1 = Tp01 * ist;
        t00 = Tp00 - kt0 * Tp00; t01 = Tp01 - kt0 * Tp01; t11 = Tp11 - kt1 * Tp01;
        float* row = gt + (size_t)t * 8;
        row[0] = kx0; row[1] = kx1; row[2] = kt0; row[3] = kt1;
        row[4] = isx; row[5] = ist; row[6] = Sx * Sx * St; row[7] = 0.f;
    }
}

// ---- main: wave = 2 trajectories; lanes = time chunks; streamed z, zero gather ----
__global__ __launch_bounds__(BT, 1) void ekf_main(const float* __restrict__ params,
                                                  const float* __restrict__ meas,
                                                  const float* __restrict__ gt,
                                                  double* __restrict__ part)
{
    __shared__ __align__(16) float lds[2 * GRAN * 4];   // 48 KB: [traj 2][1536 granules]

    const int tid = threadIdx.x;
    const int tau = tid >> 5;            // trajectory within pair
    const int k = tid & 31;              // time chunk
    const int B = blockIdx.x;
    const float dt = DTF;
    const float fric = params[0];
    const float damping = params[1];
    const float a = 1.f - dt * damping;
    const float dfr = dt * fric;
    const char* __restrict__ zb0 = (const char*)meas + (size_t)(2 * B) * (ZF * 4);

    // stream both trajectories: linear LDS dest, involution-swizzled global source
    #pragma unroll
    for (int i = 0; i < 48; ++i) {
        const int ti = i / 24, il = i % 24;
        int q = 64 * il + tid;
        int sq = swz(q);
        __builtin_amdgcn_global_load_lds(
            (const void*)(zb0 + (size_t)ti * (ZF * 4) + (size_t)sq * 16),
            (void*)&lds[4 * (ti * GRAN + 64 * il)], 16, 0, 0);
    }

    // gain rows for batch 0 (rows 0..3), wave-uniform loads
    const float4* __restrict__ gtp = (const float4*)gt;
    float4 A0 = gtp[0], A1 = gtp[1], A2 = gtp[2], A3 = gtp[3];
    float4 A4 = gtp[4], A5 = gtp[5], A6 = gtp[6], A7 = gtp[7];

    // per-lane geometry
    const int gB = 48 * ((k == 0) ? 0 : (k - 1));     // base granule (= 3*jw/4)
    const int tb = tau * GRAN;
    const int ro0 = (k == 0) ? 0 : 64;
    const int ro1 = (k == 0) ? 64 : ((k == 31) ? 127 : 128);

    asm volatile("s_waitcnt vmcnt(0)" ::: "memory");   // z + batch-0 gains resident
    __builtin_amdgcn_sched_barrier(0);

    // FD init at jw from LDS (k=0,1: exact reference init at t=0)
    float s0, s1, s2, s3, s4, s5;
    {
        float4 u0 = *(const float4*)&lds[4 * (tb + swz(gB))];
        float4 u1 = *(const float4*)&lds[4 * (tb + swz(gB + 1))];
        s0 = u0.x; s1 = u0.y; s4 = u0.z;
        s2 = (u0.w - u0.x) / dt; s3 = (u1.x - u0.y) / dt; s5 = (u1.y - u0.z) / dt;
    }

    float facc = 0.f;

#define ZREAD(M) \
    float4 v0 = *(const float4*)&lds[4 * (tb + swz(min(gB + 3*(M),     GRAN-1)))]; \
    float4 v1 = *(const float4*)&lds[4 * (tb + swz(min(gB + 3*(M) + 1, GRAN-1)))]; \
    float4 v2 = *(const float4*)&lds[4 * (tb + swz(min(gB + 3*(M) + 2, GRAN-1)))]; \
    float4 v3 = *(const float4*)&lds[4 * (tb + swz(min(gB + 3*(M) + 3, GRAN-1)))]; \
    float zv[12] = { v0.w, v1.x, v1.y, v1.z, v1.w, v2.x, \
                     v2.y, v2.z, v2.w, v3.x, v3.y, v3.z };

#define STEP(SS, GA, GB_) { \
    float p0 = fmaf(dt, s2, s0), p1 = fmaf(dt, s3, s1), p4 = fmaf(dt, s5, s4); \
    float p2 = fmaf(a, s2, -copysignf(dfr, s2)); \
    float p3 = fmaf(a, s3, -copysignf(dfr, s3)); \
    float y0 = zv[3*(SS)] - p0, y1 = zv[3*(SS)+1] - p1, y2 = zv[3*(SS)+2] - p4; \
    s0 = fmaf(GA.x, y0, p0); s1 = fmaf(GA.x, y1, p1); \
    s2 = fmaf(GA.y, y0, p2); s3 = fmaf(GA.y, y1, p3); \
    s4 = fmaf(GA.z, y2, p4); s5 = fmaf(GA.w, y2, s5); \
    int r = 4 * m + (SS); \
    if (r >= ro0 && r < ro1) \
        facc += GB_.z + GB_.x * fmaf(y0, y0, y1 * y1) + GB_.y * y2 * y2; }

    // 32 batches of 4 steps; gains double-buffered A/B (static names, rule #20)
    #pragma unroll 4
    for (int mp = 0; mp < 16; ++mp) {
        {   // batch 2mp (gains in A); prefetch batch 2mp+1 into B
            const int m = 2 * mp;
            float4 B0 = gtp[8*m+8],  B1 = gtp[8*m+9],  B2 = gtp[8*m+10], B3 = gtp[8*m+11];
            float4 B4 = gtp[8*m+12], B5 = gtp[8*m+13], B6 = gtp[8*m+14], B7 = gtp[8*m+15];
            ZREAD(m)
            STEP(0, A0, A1) STEP(1, A2, A3) STEP(2, A4, A5) STEP(3, A6, A7)
            A0=B0; A1=B1; A2=B2; A3=B3; A4=B4; A5=B5; A6=B6; A7=B7;
        }
        {   // batch 2mp+1 (gains in A after swap); prefetch 2mp+2
            const int m = 2 * mp + 1;
            const int mn = min(m + 1, 31);
            float4 B0 = gtp[8*mn],   B1 = gtp[8*mn+1], B2 = gtp[8*mn+2], B3 = gtp[8*mn+3];
            float4 B4 = gtp[8*mn+4], B5 = gtp[8*mn+5], B6 = gtp[8*mn+6], B7 = gtp[8*mn+7];
            ZREAD(m)
            STEP(0, A0, A1) STEP(1, A2, A3) STEP(2, A4, A5) STEP(3, A6, A7)
            A0=B0; A1=B1; A2=B2; A3=B3; A4=B4; A5=B5; A6=B6; A7=B7;
        }
    }
#undef STEP
#undef ZREAD

    // wave reduce over 64 lanes (covers both trajectories' owned steps)
    double acc = (double)facc;
    for (int off = 32; off; off >>= 1) acc += __shfl_down(acc, off);
    if (tid == 0) part[B] = acc;
}

// ---- finalize: reduce 1024 partials ----
__global__ void finalize_kernel(const double* __restrict__ part, float* __restrict__ out)
{
    const int tid = threadIdx.x;               // 1024 threads
    double v = part[tid];
    for (int off = 32; off; off >>= 1) v += __shfl_down(v, off);
    __shared__ double wp[16];
    if ((tid & 63) == 0) wp[tid >> 6] = v;
    __syncthreads();
    if (tid == 0) {
        double t = 0.0;
        #pragma unroll
        for (int i = 0; i < 16; ++i) t += wp[i];
        out[0] = (float)(t / ((double)Bn * (double)NS));
    }
}

extern "C" void kernel_launch(void* const* d_in, const int* in_sizes, int n_in,
                              void* d_out, int out_size, void* d_ws, size_t ws_size,
                              hipStream_t stream)
{
    const float* params = (const float*)d_in[0];
    const float* meas = (const float*)d_in[1];
    float* gt = (float*)d_ws;
    double* part = (double*)((char*)d_ws + WS_PART);
    float* out = (float*)d_out;

    hipLaunchKernelGGL(gains_kernel, dim3(1), dim3(64), 0, stream, params, gt);
    hipLaunchKernelGGL(ekf_main, dim3(NBLK), dim3(BT), 0, stream, params, meas, gt, part);
    hipLaunchKernelGGL(finalize_kernel, dim3(1), dim3(1024), 0, stream, part, out);
}

// Round 16
// 44.621 us; speedup vs baseline: 1.1381x; 1.1381x over previous
//
#include <hip/hip_runtime.h>

#define DTF (1.0f/120.0f)

constexpr int Bn = 2048, Tn = 2048, NS = Tn - 1, ZF = Tn * 3;
constexpr int BT = 64;                 // one wave = one trajectory, 64 time-chunks
constexpr int NBLK = Bn;               // 2048 blocks
constexpr int GRAN = ZF / 4;           // 1536 16B-granules per trajectory
constexpr int RROWS = 96;              // gain rows = local span

// ws: [0,3072) gain table (96 x 8 floats); [4096,...) 2048 doubles partials
constexpr int WS_PART = 4096;

__device__ __forceinline__ int swz(int q) { return q ^ ((q >> 5) & 31); }

// ---- gains: serial 2x2 Riccati from P0, 96 rows {kx0,kx1,kt0,kt1,isx,ist,det,0} ----
__global__ void gains_kernel(const float* __restrict__ params, float* __restrict__ gt)
{
    if (threadIdx.x != 0) return;
    const float dt = DTF;
    const float damping = params[1];
    const float a = 1.f - dt * damping;
    const float dt2 = dt * dt, a2 = a * a;
    const float qp = 2e-10f, qv = 3e-7f, qth = 1e-2f, qdth = 1e-1f;
    const float Rp = 2.5e-7f, Rt = 9.1e-3f;
    float x00 = 0.01f, x01 = 0.f, x11 = 0.01f;
    float t00 = 0.01f, t01 = 0.f, t11 = 0.01f;
    for (int t = 0; t < RROWS; ++t) {
        float Pp00 = fmaf(dt2, x11, fmaf(2.f * dt, x01, x00)) + qp;
        float Pp01 = a * fmaf(dt, x11, x01);
        float Pp11 = fmaf(a2, x11, qv);
        float Sx = Pp00 + Rp, isx = __builtin_amdgcn_rcpf(Sx);
        float kx0 = Pp00 * isx, kx1 = Pp01 * isx;
        x00 = Pp00 - kx0 * Pp00; x01 = Pp01 - kx0 * Pp01; x11 = Pp11 - kx1 * Pp01;
        float Tp00 = fmaf(dt2, t11, fmaf(2.f * dt, t01, t00)) + qth;
        float Tp01 = fmaf(dt, t11, t01);
        float Tp11 = t11 + qdth;
        float St = Tp00 + Rt, ist = __builtin_amdgcn_rcpf(St);
        float kt0 = Tp00 * ist, kt1 = Tp01 * ist;
        t00 = Tp00 - kt0 * Tp00; t01 = Tp01 - kt0 * Tp01; t11 = Tp11 - kt1 * Tp01;
        float* row = gt + (size_t)t * 8;
        row[0] = kx0; row[1] = kx1; row[2] = kt0; row[3] = kt1;
        row[4] = isx; row[5] = ist; row[6] = Sx * Sx * St; row[7] = 0.f;
    }
}

// ---- main: wave = 1 trajectory; 64 lanes = 64 chunks (L=32, W=64); streamed z ----
__global__ __launch_bounds__(BT, 2) void ekf_main(const float* __restrict__ params,
                                                  const float* __restrict__ meas,
                                                  const float* __restrict__ gt,
                                                  double* __restrict__ part)
{
    __shared__ __align__(16) float lds[GRAN * 4];   // 24 KB: whole trajectory

    const int tid = threadIdx.x;                    // chunk index k
    const int B = blockIdx.x;                       // trajectory
    const float dt = DTF;
    const float fric = params[0];
    const float damping = params[1];
    const float a = 1.f - dt * damping;
    const float dfr = dt * fric;
    const char* __restrict__ zb = (const char*)meas + (size_t)B * (ZF * 4);

    // stream whole trajectory: linear LDS dest, involution-swizzled source (rule #21)
    #pragma unroll
    for (int i = 0; i < 24; ++i) {
        int sq = swz(64 * i + tid);
        __builtin_amdgcn_global_load_lds((const void*)(zb + (size_t)sq * 16),
                                         (void*)&lds[256 * i], 16, 0, 0);
    }

    // gain rows for batch 0 (rows 0..3), wave-uniform loads
    const float4* __restrict__ gtp = (const float4*)gt;
    float4 A0 = gtp[0], A1 = gtp[1], A2 = gtp[2], A3 = gtp[3];
    float4 A4 = gtp[4], A5 = gtp[5], A6 = gtp[6], A7 = gtp[7];

    // per-lane geometry: k<=2 start at 0 (exact: local==global); else jw = 32(k-2)
    const int k = tid;
    const int jw = (k <= 2) ? 0 : 32 * (k - 2);
    const int gB = (3 * jw) >> 2;                  // 24*(k-2) granules, 16B-aligned
    const int ro0 = 32 * k - jw;                   // owned local window [ro0, ro1)
    const int ro1 = min(32 * k + 32, NS) - jw;

    asm volatile("s_waitcnt vmcnt(0)" ::: "memory");
    __builtin_amdgcn_sched_barrier(0);

    // FD init at jw from LDS (k<=2: exact reference init at t=0)
    float s0, s1, s2, s3, s4, s5;
    {
        float4 u0 = *(const float4*)&lds[4 * swz(gB)];
        float4 u1 = *(const float4*)&lds[4 * swz(gB + 1)];
        s0 = u0.x; s1 = u0.y; s4 = u0.z;
        s2 = (u0.w - u0.x) / dt; s3 = (u1.x - u0.y) / dt; s5 = (u1.y - u0.z) / dt;
    }

    float facc = 0.f;

#define ZREAD(M) \
    float4 v0 = *(const float4*)&lds[4 * swz(min(gB + 3*(M),     GRAN-1))]; \
    float4 v1 = *(const float4*)&lds[4 * swz(min(gB + 3*(M) + 1, GRAN-1))]; \
    float4 v2 = *(const float4*)&lds[4 * swz(min(gB + 3*(M) + 2, GRAN-1))]; \
    float4 v3 = *(const float4*)&lds[4 * swz(min(gB + 3*(M) + 3, GRAN-1))]; \
    float zv[12] = { v0.w, v1.x, v1.y, v1.z, v1.w, v2.x, \
                     v2.y, v2.z, v2.w, v3.x, v3.y, v3.z };

#define STEP(SS, GA, GB_) { \
    float p0 = fmaf(dt, s2, s0), p1 = fmaf(dt, s3, s1), p4 = fmaf(dt, s5, s4); \
    float p2 = fmaf(a, s2, -copysignf(dfr, s2)); \
    float p3 = fmaf(a, s3, -copysignf(dfr, s3)); \
    float y0 = zv[3*(SS)] - p0, y1 = zv[3*(SS)+1] - p1, y2 = zv[3*(SS)+2] - p4; \
    s0 = fmaf(GA.x, y0, p0); s1 = fmaf(GA.x, y1, p1); \
    s2 = fmaf(GA.y, y0, p2); s3 = fmaf(GA.y, y1, p3); \
    s4 = fmaf(GA.z, y2, p4); s5 = fmaf(GA.w, y2, s5); \
    int r = 4 * m + (SS); \
    if (r >= ro0 && r < ro1) \
        facc += GB_.z + GB_.x * fmaf(y0, y0, y1 * y1) + GB_.y * y2 * y2; }

    // 24 batches of 4 steps; gains double-buffered A/B (static names, rule #20)
    #pragma unroll 4
    for (int mp = 0; mp < 12; ++mp) {
        {   // batch 2mp (gains in A); prefetch batch 2mp+1 into B
            const int m = 2 * mp;
            float4 B0 = gtp[8*m+8],  B1 = gtp[8*m+9],  B2 = gtp[8*m+10], B3 = gtp[8*m+11];
            float4 B4 = gtp[8*m+12], B5 = gtp[8*m+13], B6 = gtp[8*m+14], B7 = gtp[8*m+15];
            ZREAD(m)
            STEP(0, A0, A1) STEP(1, A2, A3) STEP(2, A4, A5) STEP(3, A6, A7)
            A0=B0; A1=B1; A2=B2; A3=B3; A4=B4; A5=B5; A6=B6; A7=B7;
        }
        {   // batch 2mp+1; prefetch 2mp+2 (clamped)
            const int m = 2 * mp + 1;
            const int mn = min(m + 1, 23);
            float4 B0 = gtp[8*mn],   B1 = gtp[8*mn+1], B2 = gtp[8*mn+2], B3 = gtp[8*mn+3];
            float4 B4 = gtp[8*mn+4], B5 = gtp[8*mn+5], B6 = gtp[8*mn+6], B7 = gtp[8*mn+7];
            ZREAD(m)
            STEP(0, A0, A1) STEP(1, A2, A3) STEP(2, A4, A5) STEP(3, A6, A7)
            A0=B0; A1=B1; A2=B2; A3=B3; A4=B4; A5=B5; A6=B6; A7=B7;
        }
    }
#undef STEP
#undef ZREAD

    // wave reduce over 64 lanes (all chunks of this trajectory)
    double acc = (double)facc;
    for (int off = 32; off; off >>= 1) acc += __shfl_down(acc, off);
    if (tid == 0) part[B] = acc;
}

// ---- finalize: reduce 2048 partials ----
__global__ void finalize_kernel(const double* __restrict__ part, float* __restrict__ out)
{
    const int tid = threadIdx.x;               // 1024 threads
    double v = part[tid] + part[tid + 1024];
    for (int off = 32; off; off >>= 1) v += __shfl_down(v, off);
    __shared__ double wp[16];
    if ((tid & 63) == 0) wp[tid >> 6] = v;
    __syncthreads();
    if (tid == 0) {
        double t = 0.0;
        #pragma unroll
        for (int i = 0; i < 16; ++i) t += wp[i];
        out[0] = (float)(t / ((double)Bn * (double)NS));
    }
}

extern "C" void kernel_launch(void* const* d_in, const int* in_sizes, int n_in,
                              void* d_out, int out_size, void* d_ws, size_t ws_size,
                              hipStream_t stream)
{
    const float* params = (const float*)d_in[0];
    const float* meas = (const float*)d_in[1];
    float* gt = (float*)d_ws;
    double* part = (double*)((char*)d_ws + WS_PART);
    float* out = (float*)d_out;

    hipLaunchKernelGGL(gains_kernel, dim3(1), dim3(64), 0, stream, params, gt);
    hipLaunchKernelGGL(ekf_main, dim3(NBLK), dim3(BT), 0, stream, params, meas, gt, part);
    hipLaunchKernelGGL(finalize_kernel, dim3(1), dim3(1024), 0, stream, part, out);
}

// Round 17
// 41.186 us; speedup vs baseline: 1.2331x; 1.0834x over previous
//
#include <hip/hip_runtime.h>

#define DTF (1.0f/120.0f)

constexpr int Bn = 2048, Tn = 2048, NS = Tn - 1, ZF = Tn * 3;
constexpr int BT = 128;               // 2 waves = 1 trajectory; 128 chunks of L=16
constexpr int NBLK = Bn;              // 2048 blocks
constexpr int GRAN = ZF / 4;          // 1536 16B-granules per trajectory
constexpr int RROWS = 80;             // gain rows = local span (64 warm + 16 owned)

// ws: [0,2560) gain table (80 x 8 floats); [4096,...) 2048 doubles partials
constexpr int WS_PART = 4096;

// LDS-side-only swizzle: granule g -> byte offset (keeps 16B alignment)
__device__ __forceinline__ int ldsb(int g) { return (g << 4) ^ (((g >> 5) & 3) << 4); }

// ---- gains: serial 2x2 Riccati from P0, 80 rows {kx0,kx1,kt0,kt1,isx,ist,det,0} ----
__global__ void gains_kernel(const float* __restrict__ params, float* __restrict__ gt)
{
    if (threadIdx.x != 0) return;
    const float dt = DTF;
    const float damping = params[1];
    const float a = 1.f - dt * damping;
    const float dt2 = dt * dt, a2 = a * a;
    const float qp = 2e-10f, qv = 3e-7f, qth = 1e-2f, qdth = 1e-1f;
    const float Rp = 2.5e-7f, Rt = 9.1e-3f;
    float x00 = 0.01f, x01 = 0.f, x11 = 0.01f;
    float t00 = 0.01f, t01 = 0.f, t11 = 0.01f;
    for (int t = 0; t < RROWS; ++t) {
        float Pp00 = fmaf(dt2, x11, fmaf(2.f * dt, x01, x00)) + qp;
        float Pp01 = a * fmaf(dt, x11, x01);
        float Pp11 = fmaf(a2, x11, qv);
        float Sx = Pp00 + Rp, isx = __builtin_amdgcn_rcpf(Sx);
        float kx0 = Pp00 * isx, kx1 = Pp01 * isx;
        x00 = Pp00 - kx0 * Pp00; x01 = Pp01 - kx0 * Pp01; x11 = Pp11 - kx1 * Pp01;
        float Tp00 = fmaf(dt2, t11, fmaf(2.f * dt, t01, t00)) + qth;
        float Tp01 = fmaf(dt, t11, t01);
        float Tp11 = t11 + qdth;
        float St = Tp00 + Rt, ist = __builtin_amdgcn_rcpf(St);
        float kt0 = Tp00 * ist, kt1 = Tp01 * ist;
        t00 = Tp00 - kt0 * Tp00; t01 = Tp01 - kt0 * Tp01; t11 = Tp11 - kt1 * Tp01;
        float* row = gt + (size_t)t * 8;
        row[0] = kx0; row[1] = kx1; row[2] = kt0; row[3] = kt1;
        row[4] = isx; row[5] = ist; row[6] = Sx * Sx * St; row[7] = 0.f;
    }
}

// ---- main: 2 waves per trajectory; 128 lanes = L=16 chunks; coalesced reg-stage ----
__global__ __launch_bounds__(BT, 3) void ekf_main(const float* __restrict__ params,
                                                  const float* __restrict__ meas,
                                                  const float* __restrict__ gt,
                                                  double* __restrict__ part)
{
    __shared__ __align__(16) float lds[GRAN * 4];   // 24 KB: whole trajectory (swizzled)
    __shared__ double wsum[2];

    const int tid = threadIdx.x;                    // chunk index c
    const int B = blockIdx.x;                       // trajectory
    const float dt = DTF;
    const float fric = params[0];
    const float damping = params[1];
    const float a = 1.f - dt * damping;
    const float dfr = dt * fric;
    const char* __restrict__ zb = (const char*)meas + (size_t)B * (ZF * 4);
    char* __restrict__ ldsc = (char*)lds;

    // coalesced stage: lane-linear global loads (full 128B lines), swizzled LDS writes
    float4 st[12];
    #pragma unroll
    for (int i = 0; i < 12; ++i)
        st[i] = *(const float4*)(zb + (size_t)(128 * i + tid) * 16);

    // gain rows for batch 0 while loads are in flight (wave-uniform)
    const float4* __restrict__ gtp = (const float4*)gt;
    float4 A0 = gtp[0], A1 = gtp[1], A2 = gtp[2], A3 = gtp[3];
    float4 A4 = gtp[4], A5 = gtp[5], A6 = gtp[6], A7 = gtp[7];

    #pragma unroll
    for (int i = 0; i < 12; ++i) {
        int g = 128 * i + tid;
        *(float4*)(ldsc + ldsb(g)) = st[i];
    }
    __syncthreads();                                // staging visible to both waves

    // per-lane geometry: c<=4 exact from t=0; else jw = 16c-64 (W=64)
    const int c = tid;
    const int jw = (c <= 4) ? 0 : (16 * c - 64);
    const int gB = (3 * jw) >> 2;                   // 16B-aligned (jw % 4 == 0)
    const int ro0 = 16 * c - jw;                    // owned local window [ro0, ro1)
    const int ro1 = min(16 * c + 16, NS) - jw;

    // FD init at jw (c<=4: exact reference init)
    float s0, s1, s2, s3, s4, s5;
    {
        float4 u0 = *(const float4*)(ldsc + ldsb(gB));
        float4 u1 = *(const float4*)(ldsc + ldsb(gB + 1));
        s0 = u0.x; s1 = u0.y; s4 = u0.z;
        s2 = (u0.w - u0.x) / dt; s3 = (u1.x - u0.y) / dt; s5 = (u1.y - u0.z) / dt;
    }

    float facc = 0.f;

#define ZREAD(M) \
    float4 v0 = *(const float4*)(ldsc + ldsb(min(gB + 3*(M),     GRAN-1))); \
    float4 v1 = *(const float4*)(ldsc + ldsb(min(gB + 3*(M) + 1, GRAN-1))); \
    float4 v2 = *(const float4*)(ldsc + ldsb(min(gB + 3*(M) + 2, GRAN-1))); \
    float4 v3 = *(const float4*)(ldsc + ldsb(min(gB + 3*(M) + 3, GRAN-1))); \
    float zv[12] = { v0.w, v1.x, v1.y, v1.z, v1.w, v2.x, \
                     v2.y, v2.z, v2.w, v3.x, v3.y, v3.z };

#define STEP(SS, GA, GB_) { \
    float p0 = fmaf(dt, s2, s0), p1 = fmaf(dt, s3, s1), p4 = fmaf(dt, s5, s4); \
    float p2 = fmaf(a, s2, -copysignf(dfr, s2)); \
    float p3 = fmaf(a, s3, -copysignf(dfr, s3)); \
    float y0 = zv[3*(SS)] - p0, y1 = zv[3*(SS)+1] - p1, y2 = zv[3*(SS)+2] - p4; \
    s0 = fmaf(GA.x, y0, p0); s1 = fmaf(GA.x, y1, p1); \
    s2 = fmaf(GA.y, y0, p2); s3 = fmaf(GA.y, y1, p3); \
    s4 = fmaf(GA.z, y2, p4); s5 = fmaf(GA.w, y2, s5); \
    int r = 4 * m + (SS); \
    if (r >= ro0 && r < ro1) \
        facc += GB_.z + GB_.x * fmaf(y0, y0, y1 * y1) + GB_.y * y2 * y2; }

    // 20 batches of 4 steps; gains double-buffered A/B (static names, rule #20)
    #pragma unroll 2
    for (int mp = 0; mp < 10; ++mp) {
        {   // batch 2mp (gains in A); prefetch batch 2mp+1 into B
            const int m = 2 * mp;
            float4 B0 = gtp[8*m+8],  B1 = gtp[8*m+9],  B2 = gtp[8*m+10], B3 = gtp[8*m+11];
            float4 B4 = gtp[8*m+12], B5 = gtp[8*m+13], B6 = gtp[8*m+14], B7 = gtp[8*m+15];
            ZREAD(m)
            STEP(0, A0, A1) STEP(1, A2, A3) STEP(2, A4, A5) STEP(3, A6, A7)
            A0=B0; A1=B1; A2=B2; A3=B3; A4=B4; A5=B5; A6=B6; A7=B7;
        }
        {   // batch 2mp+1; prefetch 2mp+2 (clamped)
            const int m = 2 * mp + 1;
            const int mn = min(m + 1, 19);
            float4 B0 = gtp[8*mn],   B1 = gtp[8*mn+1], B2 = gtp[8*mn+2], B3 = gtp[8*mn+3];
            float4 B4 = gtp[8*mn+4], B5 = gtp[8*mn+5], B6 = gtp[8*mn+6], B7 = gtp[8*mn+7];
            ZREAD(m)
            STEP(0, A0, A1) STEP(1, A2, A3) STEP(2, A4, A5) STEP(3, A6, A7)
            A0=B0; A1=B1; A2=B2; A3=B3; A4=B4; A5=B5; A6=B6; A7=B7;
        }
    }
#undef STEP
#undef ZREAD

    // per-wave reduce, then block sum (covers all 128 chunks = whole trajectory)
    double acc = (double)facc;
    for (int off = 32; off; off >>= 1) acc += __shfl_down(acc, off);
    if ((tid & 63) == 0) wsum[tid >> 6] = acc;
    __syncthreads();
    if (tid == 0) part[B] = wsum[0] + wsum[1];
}

// ---- finalize: reduce 2048 partials ----
__global__ void finalize_kernel(const double* __restrict__ part, float* __restrict__ out)
{
    const int tid = threadIdx.x;               // 1024 threads
    double v = part[tid] + part[tid + 1024];
    for (int off = 32; off; off >>= 1) v += __shfl_down(v, off);
    __shared__ double wp[16];
    if ((tid & 63) == 0) wp[tid >> 6] = v;
    __syncthreads();
    if (tid == 0) {
        double t = 0.0;
        #pragma unroll
        for (int i = 0; i < 16; ++i) t += wp[i];
        out[0] = (float)(t / ((double)Bn * (double)NS));
    }
}

extern "C" void kernel_launch(void* const* d_in, const int* in_sizes, int n_in,
                              void* d_out, int out_size, void* d_ws, size_t ws_size,
                              hipStream_t stream)
{
    const float* params = (const float*)d_in[0];
    const float* meas = (const float*)d_in[1];
    float* gt = (float*)d_ws;
    double* part = (double*)((char*)d_ws + WS_PART);
    float* out = (float*)d_out;

    hipLaunchKernelGGL(gains_kernel, dim3(1), dim3(64), 0, stream, params, gt);
    hipLaunchKernelGGL(ekf_main, dim3(NBLK), dim3(BT), 0, stream, params, meas, gt, part);
    hipLaunchKernelGGL(finalize_kernel, dim3(1), dim3(1024), 0, stream, part, out);
}